// Round 1
// baseline (364.301 us; speedup 1.0000x reference)
//
#include <hip/hip_runtime.h>
#include <climits>
#include <cmath>

// DetectPeaks: xcorr [16,1,256,8192] f32 -> (neighbor_score [.,3], topk_scores [.,3], topk_index [.,3])
// 4096 rows x 8192 lags. One block per row, LDS-staged, top-3 reduction.

#define PW    8192          // lag axis length (W)
#define PNLAG (PW / 2)      // 4096
#define BLOCK 256

__device__ __forceinline__ bool better(float av, int ai, float bv, int bi) {
  // lax.top_k order: higher value first; ties -> lower index first
  return (av > bv) || ((av == bv) && (ai < bi));
}

__device__ __forceinline__ void insert3(float v, int i,
                                        float &v0, int &i0,
                                        float &v1, int &i1,
                                        float &v2, int &i2) {
  if (better(v, i, v2, i2)) {
    if (better(v, i, v1, i1)) {
      if (better(v, i, v0, i0)) {
        v2 = v1; i2 = i1; v1 = v0; i1 = i0; v0 = v; i0 = i;
      } else {
        v2 = v1; i2 = i1; v1 = v; i1 = i;
      }
    } else {
      v2 = v; i2 = i;
    }
  }
}

__global__ __launch_bounds__(BLOCK)
void detect_peaks_kernel(const float* __restrict__ x,
                         float* __restrict__ out,
                         int rows) {
  __shared__ float sx[PW];     // the whole row, original values
  __shared__ float rv[12];     // per-wave top-3 values (4 waves x 3)
  __shared__ int   ri[12];     // per-wave top-3 indices

  const int row = blockIdx.x;
  const int t   = threadIdx.x;
  const float* __restrict__ xr = x + (size_t)row * PW;

  // ---- stage row to LDS: coalesced float4, conflict-free ----
  const float4* __restrict__ xv = (const float4*)xr;
  float4* sv = (float4*)sx;
#pragma unroll
  for (int j = 0; j < PW / 4; j += BLOCK) {
    sv[j + t] = xv[j + t];
  }
  __syncthreads();

  // ---- per-thread top-3 over strided elements ----
  float v0 = -INFINITY, v1 = -INFINITY, v2 = -INFINITY;
  int   i0 = INT_MAX,   i1 = INT_MAX,   i2 = INT_MAX;

#pragma unroll 4
  for (int j = 0; j < PW; j += BLOCK) {
    const int i   = j + t;
    const float s = sx[i];
    const float l = (i > 0)      ? sx[i - 1] : -INFINITY;
    const float r = (i < PW - 1) ? sx[i + 1] : -INFINITY;
    const float m = fmaxf(fmaxf(l, r), s);
    const float sc = (s == m) ? s : 0.0f;   // x * keep  (non-peak -> 0)
    insert3(sc, i, v0, i0, v1, i1, v2, i2);
  }

  // ---- wave-level tree merge (wave = 64 lanes) ----
  const int lane = t & 63;
  const int wave = t >> 6;
#pragma unroll
  for (int off = 32; off > 0; off >>= 1) {
    // gather BEFORE inserting, so we read pre-merge registers
    float ov0 = __shfl_down(v0, off);
    int   oi0 = __shfl_down(i0, off);
    float ov1 = __shfl_down(v1, off);
    int   oi1 = __shfl_down(i1, off);
    float ov2 = __shfl_down(v2, off);
    int   oi2 = __shfl_down(i2, off);
    if (lane + off < 64) {   // guard against OOB-shfl self-merge duplicates
      insert3(ov0, oi0, v0, i0, v1, i1, v2, i2);
      insert3(ov1, oi1, v0, i0, v1, i1, v2, i2);
      insert3(ov2, oi2, v0, i0, v1, i1, v2, i2);
    }
  }

  if (lane == 0) {
    rv[wave * 3 + 0] = v0; ri[wave * 3 + 0] = i0;
    rv[wave * 3 + 1] = v1; ri[wave * 3 + 1] = i1;
    rv[wave * 3 + 2] = v2; ri[wave * 3 + 2] = i2;
  }
  __syncthreads();

  // ---- thread 0: merge 4 wave results, write outputs ----
  if (t == 0) {
#pragma unroll
    for (int w = 1; w < 4; ++w) {
      insert3(rv[w * 3 + 0], ri[w * 3 + 0], v0, i0, v1, i1, v2, i2);
      insert3(rv[w * 3 + 1], ri[w * 3 + 1], v0, i0, v1, i1, v2, i2);
      insert3(rv[w * 3 + 2], ri[w * 3 + 2], v0, i0, v1, i1, v2, i2);
    }

    float* __restrict__ nb = out;                      // neighbor_score [rows*3]
    float* __restrict__ ts = out + (size_t)rows * 3;   // topk_scores    [rows*3]
    float* __restrict__ ti = out + (size_t)rows * 6;   // topk_index     [rows*3] (as float)

    const int top = i0;
#pragma unroll
    for (int k = 0; k < 3; ++k) {
      int idx = top - 1 + k;
      idx = idx < 0 ? 0 : (idx > PW - 1 ? PW - 1 : idx);
      nb[row * 3 + k] = sx[idx];
    }
    ts[row * 3 + 0] = v0;
    ts[row * 3 + 1] = v1;
    ts[row * 3 + 2] = v2;
    ti[row * 3 + 0] = (float)(i0 - PNLAG);
    ti[row * 3 + 1] = (float)(i1 - PNLAG);
    ti[row * 3 + 2] = (float)(i2 - PNLAG);
  }
}

extern "C" void kernel_launch(void* const* d_in, const int* in_sizes, int n_in,
                              void* d_out, int out_size, void* d_ws, size_t ws_size,
                              hipStream_t stream) {
  const float* x = (const float*)d_in[0];
  float* out = (float*)d_out;
  const int rows = in_sizes[0] / PW;   // 16*1*256 = 4096
  detect_peaks_kernel<<<rows, BLOCK, 0, stream>>>(x, out, rows);
}

// Round 2
// 247.425 us; speedup vs baseline: 1.4724x; 1.4724x over previous
//
#include <hip/hip_runtime.h>
#include <climits>
#include <cmath>

// DetectPeaks: xcorr [16,1,256,8192] f32 -> (neighbor_score, topk_scores, topk_index), each [rows,3]
// rows = 4096, W = 8192. One block per row, NO LDS staging: direct vectorized global reads,
// per-quad top-2 pruning (<=2 local maxima per 4 contiguous lags), register top-3, shfl-tree merge.

#define PW    8192
#define PNLAG (PW / 2)
#define BLOCK 256
#define QPT   (PW / 4 / BLOCK)   // 8 float4-quads per thread

__device__ __forceinline__ bool better(float av, int ai, float bv, int bi) {
  // lax.top_k order: higher value first; ties -> lower index
  return (av > bv) || ((av == bv) && (ai < bi));
}

__device__ __forceinline__ void insert3_full(float v, int i,
                                             float &v0, int &i0,
                                             float &v1, int &i1,
                                             float &v2, int &i2) {
  if (better(v, i, v2, i2)) {
    if (better(v, i, v1, i1)) {
      if (better(v, i, v0, i0)) {
        v2 = v1; i2 = i1; v1 = v0; i1 = i0; v0 = v; i0 = i;
      } else {
        v2 = v1; i2 = i1; v1 = v; i1 = i;
      }
    } else {
      v2 = v; i2 = i;
    }
  }
}

// Candidate index is (almost) always fresh/higher than held entries; exact float ties
// between distinct lags have probability ~0, so strict > is sufficient here.
__device__ __forceinline__ void insert3_fast(float c, int ci,
                                             float &v0, int &i0,
                                             float &v1, int &i1,
                                             float &v2, int &i2) {
  const bool b2 = c > v2;
  const bool b1 = c > v1;
  const bool b0 = c > v0;
  v2 = b1 ? v1 : (b2 ? c : v2);  i2 = b1 ? i1 : (b2 ? ci : i2);
  v1 = b0 ? v0 : (b1 ? c : v1);  i1 = b0 ? i0 : (b1 ? ci : i1);
  v0 = b0 ? c  : v0;             i0 = b0 ? ci : i0;
}

__global__ __launch_bounds__(BLOCK)
void detect_peaks_kernel(const float* __restrict__ x,
                         float* __restrict__ out,
                         int rows) {
  __shared__ float rv[12];
  __shared__ int   ri[12];

  const int row = blockIdx.x;
  const int t   = threadIdx.x;
  const float* __restrict__ xr = x + (size_t)row * PW;
  const float4* __restrict__ xv = (const float4*)xr;

  float v0 = -INFINITY, v1 = -INFINITY, v2 = -INFINITY;
  int   i0 = INT_MAX,   i1 = INT_MAX,   i2 = INT_MAX;

#pragma unroll
  for (int j = 0; j < QPT; ++j) {
    const int q = j * BLOCK + t;        // quad index within row
    const int p = q * 4;                // element index of v.x
    const float4 v = xv[q];
    const float left  = (p > 0)        ? xr[p - 1] : -INFINITY;  // L1-hit scalar
    const float right = (p + 4 < PW)   ? xr[p + 4] : -INFINITY;  // L1-hit scalar

    // sliding 3-max for the 4 positions
    const float p01 = fmaxf(v.x, v.y);
    const float p12 = fmaxf(v.y, v.z);
    const float p23 = fmaxf(v.z, v.w);
    const float m0 = fmaxf(left, p01);
    const float m1 = fmaxf(p01, v.z);
    const float m2 = fmaxf(p12, v.w);
    const float m3 = fmaxf(p23, right);

    // NMS score: x where local max else 0 (matches x*keep; sign of zero irrelevant here)
    const float s0 = (v.x == m0) ? v.x : 0.0f;
    const float s1 = (v.y == m1) ? v.y : 0.0f;
    const float s2 = (v.z == m2) ? v.z : 0.0f;
    const float s3 = (v.w == m3) ? v.w : 0.0f;

    // quad top-2 (>= implements tie->lower-index since left arg always has lower index)
    const bool  a01 = s0 >= s1;
    const float hiA = a01 ? s0 : s1;   const int hiAi = a01 ? p     : p + 1;
    const float loA = a01 ? s1 : s0;   const int loAi = a01 ? p + 1 : p;
    const bool  a23 = s2 >= s3;
    const float hiB = a23 ? s2 : s3;   const int hiBi = a23 ? p + 2 : p + 3;
    const float loB = a23 ? s3 : s2;   const int loBi = a23 ? p + 3 : p + 2;

    const bool  ab  = hiA >= hiB;
    const float c1  = ab ? hiA : hiB;  const int c1i = ab ? hiAi : hiBi;
    // second best: max(loser-of-final, winner-pair's low) — left arg always lower index
    const bool  sb  = ab ? (loA >= hiB) : (hiA >= loB);
    const float c2  = ab ? (sb ? loA : hiB) : (sb ? hiA : loB);
    const int   c2i = ab ? (sb ? loAi : hiBi) : (sb ? hiAi : loBi);

    insert3_fast(c1, c1i, v0, i0, v1, i1, v2, i2);
    insert3_fast(c2, c2i, v0, i0, v1, i1, v2, i2);
  }

  // ---- wave-level tree merge (64 lanes) ----
  const int lane = t & 63;
  const int wave = t >> 6;
#pragma unroll
  for (int off = 32; off > 0; off >>= 1) {
    float ov0 = __shfl_down(v0, off);
    int   oi0 = __shfl_down(i0, off);
    float ov1 = __shfl_down(v1, off);
    int   oi1 = __shfl_down(i1, off);
    float ov2 = __shfl_down(v2, off);
    int   oi2 = __shfl_down(i2, off);
    if (lane + off < 64) {
      insert3_full(ov0, oi0, v0, i0, v1, i1, v2, i2);
      insert3_full(ov1, oi1, v0, i0, v1, i1, v2, i2);
      insert3_full(ov2, oi2, v0, i0, v1, i1, v2, i2);
    }
  }

  if (lane == 0) {
    rv[wave * 3 + 0] = v0; ri[wave * 3 + 0] = i0;
    rv[wave * 3 + 1] = v1; ri[wave * 3 + 1] = i1;
    rv[wave * 3 + 2] = v2; ri[wave * 3 + 2] = i2;
  }
  __syncthreads();

  if (t == 0) {
#pragma unroll
    for (int w = 1; w < 4; ++w) {
      insert3_full(rv[w * 3 + 0], ri[w * 3 + 0], v0, i0, v1, i1, v2, i2);
      insert3_full(rv[w * 3 + 1], ri[w * 3 + 1], v0, i0, v1, i1, v2, i2);
      insert3_full(rv[w * 3 + 2], ri[w * 3 + 2], v0, i0, v1, i1, v2, i2);
    }

    float* __restrict__ nb = out;                      // neighbor_score
    float* __restrict__ ts = out + (size_t)rows * 3;   // topk_scores
    float* __restrict__ ti = out + (size_t)rows * 6;   // topk_index (float)

    const int top = i0;
#pragma unroll
    for (int k = 0; k < 3; ++k) {
      int idx = top - 1 + k;
      idx = idx < 0 ? 0 : (idx > PW - 1 ? PW - 1 : idx);
      nb[row * 3 + k] = xr[idx];                       // L2-hit (just streamed)
    }
    ts[row * 3 + 0] = v0;
    ts[row * 3 + 1] = v1;
    ts[row * 3 + 2] = v2;
    ti[row * 3 + 0] = (float)(i0 - PNLAG);
    ti[row * 3 + 1] = (float)(i1 - PNLAG);
    ti[row * 3 + 2] = (float)(i2 - PNLAG);
  }
}

extern "C" void kernel_launch(void* const* d_in, const int* in_sizes, int n_in,
                              void* d_out, int out_size, void* d_ws, size_t ws_size,
                              hipStream_t stream) {
  const float* x = (const float*)d_in[0];
  float* out = (float*)d_out;
  const int rows = in_sizes[0] / PW;   // 4096
  detect_peaks_kernel<<<rows, BLOCK, 0, stream>>>(x, out, rows);
}

// Round 3
// 239.848 us; speedup vs baseline: 1.5189x; 1.0316x over previous
//
#include <hip/hip_runtime.h>
#include <climits>
#include <cmath>

// DetectPeaks: xcorr [16,1,256,8192] f32 -> (neighbor_score, topk_scores, topk_index), each [rows,3]
// rows = 4096, W = 8192. One block (4 waves) per row.
// Wave-local quad layout: wave w owns quads [w*512, (w+1)*512), thread does quad = base + j*64 + lane.
// All 8 float4 loads issued upfront (8 outstanding dwordx4/wave); neighbors resolved via shfl
// within the wave (only 2 global edge loads per wave). Per-quad top-2 pruning -> register top-3.

#define PW    8192
#define PNLAG (PW / 2)
#define BLOCK 256
#define NW    4                 // waves per block
#define J     8                 // quads per thread
// per-wave span: J*64 = 512 quads = 2048 elements

__device__ __forceinline__ bool better(float av, int ai, float bv, int bi) {
  return (av > bv) || ((av == bv) && (ai < bi));   // lax.top_k: ties -> lower index
}

__device__ __forceinline__ void insert3_full(float v, int i,
                                             float &v0, int &i0,
                                             float &v1, int &i1,
                                             float &v2, int &i2) {
  if (better(v, i, v2, i2)) {
    if (better(v, i, v1, i1)) {
      if (better(v, i, v0, i0)) {
        v2 = v1; i2 = i1; v1 = v0; i1 = i0; v0 = v; i0 = i;
      } else {
        v2 = v1; i2 = i1; v1 = v; i1 = i;
      }
    } else {
      v2 = v; i2 = i;
    }
  }
}

// Exact float ties between distinct lags have ~0 probability; strict > suffices here.
__device__ __forceinline__ void insert3_fast(float c, int ci,
                                             float &v0, int &i0,
                                             float &v1, int &i1,
                                             float &v2, int &i2) {
  const bool b2 = c > v2;
  const bool b1 = c > v1;
  const bool b0 = c > v0;
  v2 = b1 ? v1 : (b2 ? c : v2);  i2 = b1 ? i1 : (b2 ? ci : i2);
  v1 = b0 ? v0 : (b1 ? c : v1);  i1 = b0 ? i0 : (b1 ? ci : i1);
  v0 = b0 ? c  : v0;             i0 = b0 ? ci : i0;
}

__global__ __launch_bounds__(BLOCK)
void detect_peaks_kernel(const float* __restrict__ x,
                         float* __restrict__ out,
                         int rows) {
  __shared__ float rv[12];
  __shared__ int   ri[12];

  const int row  = blockIdx.x;
  const int t    = threadIdx.x;
  const int lane = t & 63;
  const int wave = t >> 6;
  const float* __restrict__ xr = x + (size_t)row * PW;
  const float4* __restrict__ xv = (const float4*)xr;

  const int waveQ = wave * (J * 64);      // first quad of this wave's span

  // ---- batch-issue all loads: 8 dwordx4 + (edge lanes) 1 scalar, all independent ----
  float4 q[J];
#pragma unroll
  for (int j = 0; j < J; ++j) {
    q[j] = xv[waveQ + j * 64 + lane];
  }
  float leftEdge  = -INFINITY;
  float rightEdge = -INFINITY;
  if (lane == 0 && wave > 0)      leftEdge  = xr[waveQ * 4 - 1];
  if (lane == 63 && wave < NW - 1) rightEdge = xr[(waveQ + J * 64) * 4];

  float v0 = -INFINITY, v1 = -INFINITY, v2 = -INFINITY;
  int   i0 = INT_MAX,   i1 = INT_MAX,   i2 = INT_MAX;

#pragma unroll
  for (int j = 0; j < J; ++j) {
    const int p = (waveQ + j * 64 + lane) * 4;
    const float4 v = q[j];

    // left neighbor of v.x: lane>0 -> lane-1's q[j].w ; lane 0 -> lane63's q[j-1].w (or edge)
    const float lu = __shfl_up(v.w, 1);
    const float l0 = (j > 0) ? __shfl(q[j - 1].w, 63) : leftEdge;
    const float left = (lane == 0) ? l0 : lu;
    // right neighbor of v.w: lane<63 -> lane+1's q[j].x ; lane 63 -> lane0's q[j+1].x (or edge)
    const float rd = __shfl_down(v.x, 1);
    const float r0 = (j < J - 1) ? __shfl(q[j + 1].x, 0) : rightEdge;
    const float right = (lane == 63) ? r0 : rd;

    // sliding 3-max over the 4 positions
    const float p01 = fmaxf(v.x, v.y);
    const float p12 = fmaxf(v.y, v.z);
    const float p23 = fmaxf(v.z, v.w);
    const float m0 = fmaxf(left, p01);
    const float m1 = fmaxf(p01, v.z);
    const float m2 = fmaxf(p12, v.w);
    const float m3 = fmaxf(p23, right);

    // NMS score: x where local max else 0
    const float s0 = (v.x == m0) ? v.x : 0.0f;
    const float s1 = (v.y == m1) ? v.y : 0.0f;
    const float s2 = (v.z == m2) ? v.z : 0.0f;
    const float s3 = (v.w == m3) ? v.w : 0.0f;

    // quad top-2 (left arg of >= always lower index => tie->lower-index preserved);
    // a 4-window of contiguous lags holds at most 2 local maxima.
    const bool  a01 = s0 >= s1;
    const float hiA = a01 ? s0 : s1;   const int hiAi = a01 ? p     : p + 1;
    const float loA = a01 ? s1 : s0;   const int loAi = a01 ? p + 1 : p;
    const bool  a23 = s2 >= s3;
    const float hiB = a23 ? s2 : s3;   const int hiBi = a23 ? p + 2 : p + 3;
    const float loB = a23 ? s3 : s2;   const int loBi = a23 ? p + 3 : p + 2;

    const bool  ab  = hiA >= hiB;
    const float c1  = ab ? hiA : hiB;  const int c1i = ab ? hiAi : hiBi;
    const bool  sb  = ab ? (loA >= hiB) : (hiA >= loB);
    const float c2  = ab ? (sb ? loA : hiB) : (sb ? hiA : loB);
    const int   c2i = ab ? (sb ? loAi : hiBi) : (sb ? hiAi : loBi);

    insert3_fast(c1, c1i, v0, i0, v1, i1, v2, i2);
    insert3_fast(c2, c2i, v0, i0, v1, i1, v2, i2);
  }

  // ---- wave-level tree merge (64 lanes) ----
#pragma unroll
  for (int off = 32; off > 0; off >>= 1) {
    float ov0 = __shfl_down(v0, off);
    int   oi0 = __shfl_down(i0, off);
    float ov1 = __shfl_down(v1, off);
    int   oi1 = __shfl_down(i1, off);
    float ov2 = __shfl_down(v2, off);
    int   oi2 = __shfl_down(i2, off);
    if (lane + off < 64) {
      insert3_full(ov0, oi0, v0, i0, v1, i1, v2, i2);
      insert3_full(ov1, oi1, v0, i0, v1, i1, v2, i2);
      insert3_full(ov2, oi2, v0, i0, v1, i1, v2, i2);
    }
  }

  if (lane == 0) {
    rv[wave * 3 + 0] = v0; ri[wave * 3 + 0] = i0;
    rv[wave * 3 + 1] = v1; ri[wave * 3 + 1] = i1;
    rv[wave * 3 + 2] = v2; ri[wave * 3 + 2] = i2;
  }
  __syncthreads();

  if (t == 0) {
#pragma unroll
    for (int w = 1; w < NW; ++w) {
      insert3_full(rv[w * 3 + 0], ri[w * 3 + 0], v0, i0, v1, i1, v2, i2);
      insert3_full(rv[w * 3 + 1], ri[w * 3 + 1], v0, i0, v1, i1, v2, i2);
      insert3_full(rv[w * 3 + 2], ri[w * 3 + 2], v0, i0, v1, i1, v2, i2);
    }

    float* __restrict__ nb = out;                      // neighbor_score
    float* __restrict__ ts = out + (size_t)rows * 3;   // topk_scores
    float* __restrict__ ti = out + (size_t)rows * 6;   // topk_index (as float)

    const int top = i0;
#pragma unroll
    for (int k = 0; k < 3; ++k) {
      int idx = top - 1 + k;
      idx = idx < 0 ? 0 : (idx > PW - 1 ? PW - 1 : idx);
      nb[row * 3 + k] = xr[idx];                       // L2-warm
    }
    ts[row * 3 + 0] = v0;
    ts[row * 3 + 1] = v1;
    ts[row * 3 + 2] = v2;
    ti[row * 3 + 0] = (float)(i0 - PNLAG);
    ti[row * 3 + 1] = (float)(i1 - PNLAG);
    ti[row * 3 + 2] = (float)(i2 - PNLAG);
  }
}

extern "C" void kernel_launch(void* const* d_in, const int* in_sizes, int n_in,
                              void* d_out, int out_size, void* d_ws, size_t ws_size,
                              hipStream_t stream) {
  const float* x = (const float*)d_in[0];
  float* out = (float*)d_out;
  const int rows = in_sizes[0] / PW;   // 4096
  detect_peaks_kernel<<<rows, BLOCK, 0, stream>>>(x, out, rows);
}

// Round 4
// 234.086 us; speedup vs baseline: 1.5563x; 1.0246x over previous
//
#include <hip/hip_runtime.h>
#include <climits>
#include <cmath>

// DetectPeaks: xcorr [16,1,256,8192] f32 -> (neighbor_score, topk_scores, topk_index), each [rows,3]
// rows = 4096, W = 8192. One block (4 waves) per row.
// Round-4 structure: async global->LDS DMA staging (global_load_lds width=16, zero VGPR cost,
// all 32 block loads in flight simultaneously) -> one barrier -> LDS scan with per-quad
// top-2 pruning -> register top-3 -> shfl-tree wave merge -> block merge.

#define PW    8192
#define PNLAG (PW / 2)
#define BLOCK 256
#define NW    4                 // waves per block
#define J     8                 // quads per thread (wave span = J*64 quads = 2048 elems)

typedef __attribute__((address_space(1))) const void global_cv;
typedef __attribute__((address_space(3))) void lds_v;

__device__ __forceinline__ bool better(float av, int ai, float bv, int bi) {
  return (av > bv) || ((av == bv) && (ai < bi));   // lax.top_k: ties -> lower index
}

__device__ __forceinline__ void insert3_full(float v, int i,
                                             float &v0, int &i0,
                                             float &v1, int &i1,
                                             float &v2, int &i2) {
  if (better(v, i, v2, i2)) {
    if (better(v, i, v1, i1)) {
      if (better(v, i, v0, i0)) {
        v2 = v1; i2 = i1; v1 = v0; i1 = i0; v0 = v; i0 = i;
      } else {
        v2 = v1; i2 = i1; v1 = v; i1 = i;
      }
    } else {
      v2 = v; i2 = i;
    }
  }
}

// Exact float ties between distinct lags have ~0 probability; strict > suffices.
__device__ __forceinline__ void insert3_fast(float c, int ci,
                                             float &v0, int &i0,
                                             float &v1, int &i1,
                                             float &v2, int &i2) {
  const bool b2 = c > v2;
  const bool b1 = c > v1;
  const bool b0 = c > v0;
  v2 = b1 ? v1 : (b2 ? c : v2);  i2 = b1 ? i1 : (b2 ? ci : i2);
  v1 = b0 ? v0 : (b1 ? c : v1);  i1 = b0 ? i0 : (b1 ? ci : i1);
  v0 = b0 ? c  : v0;             i0 = b0 ? ci : i0;
}

__global__ __launch_bounds__(BLOCK)
void detect_peaks_kernel(const float* __restrict__ x,
                         float* __restrict__ out,
                         int rows) {
  __shared__ float sx[PW];     // full row
  __shared__ float rv[12];     // per-wave top-3 values
  __shared__ int   ri[12];     // per-wave top-3 indices

  const int row  = blockIdx.x;
  const int t    = threadIdx.x;
  const int lane = t & 63;
  const int wave = t >> 6;
  const float* __restrict__ xr = x + (size_t)row * PW;

  const int waveQ = wave * (J * 64);      // first quad of this wave's staging span

  // ---- async DMA stage: 8 global_load_lds_dwordx4 per wave, zero VGPR cost, all in flight ----
  // HW semantics: per-lane global vaddr; LDS dst = wave-uniform base + lane*16.
#pragma unroll
  for (int j = 0; j < J; ++j) {
    const float* gsrc = xr + (size_t)(waveQ + j * 64 + lane) * 4;
    float*       ldst = sx + (size_t)(waveQ + j * 64) * 4;      // wave-uniform base
    __builtin_amdgcn_global_load_lds((global_cv*)gsrc, (lds_v*)ldst, 16, 0, 0);
  }
  __syncthreads();   // drains vmcnt(0): all 32 DMAs of the block complete; row visible block-wide

  // ---- scan own span from LDS: per-quad top-2 pruning -> register top-3 ----
  float v0 = -INFINITY, v1 = -INFINITY, v2 = -INFINITY;
  int   i0 = INT_MAX,   i1 = INT_MAX,   i2 = INT_MAX;

#pragma unroll
  for (int j = 0; j < J; ++j) {
    const int p = (waveQ + j * 64 + lane) * 4;      // first element of this quad
    const float4 v = *(const float4*)(sx + p);      // ds_read_b128, lane-contiguous

    const int   li = (p == 0) ? 0 : p - 1;          // clamp addr, select -inf
    const float left  = (p == 0)      ? -INFINITY : sx[li];
    const int   riq = (p + 4 >= PW) ? PW - 1 : p + 4;
    const float right = (p + 4 >= PW) ? -INFINITY : sx[riq];

    // sliding 3-max over the 4 positions
    const float p01 = fmaxf(v.x, v.y);
    const float p12 = fmaxf(v.y, v.z);
    const float p23 = fmaxf(v.z, v.w);
    const float m0 = fmaxf(left, p01);
    const float m1 = fmaxf(p01, v.z);
    const float m2 = fmaxf(p12, v.w);
    const float m3 = fmaxf(p23, right);

    // NMS score: x where local max else 0
    const float s0 = (v.x == m0) ? v.x : 0.0f;
    const float s1 = (v.y == m1) ? v.y : 0.0f;
    const float s2 = (v.z == m2) ? v.z : 0.0f;
    const float s3 = (v.w == m3) ? v.w : 0.0f;

    // quad top-2 (left arg of >= always lower index => tie->lower-index preserved);
    // a window of 4 contiguous lags holds at most 2 local maxima.
    const bool  a01 = s0 >= s1;
    const float hiA = a01 ? s0 : s1;   const int hiAi = a01 ? p     : p + 1;
    const float loA = a01 ? s1 : s0;   const int loAi = a01 ? p + 1 : p;
    const bool  a23 = s2 >= s3;
    const float hiB = a23 ? s2 : s3;   const int hiBi = a23 ? p + 2 : p + 3;
    const float loB = a23 ? s3 : s2;   const int loBi = a23 ? p + 3 : p + 2;

    const bool  ab  = hiA >= hiB;
    const float c1  = ab ? hiA : hiB;  const int c1i = ab ? hiAi : hiBi;
    const bool  sb  = ab ? (loA >= hiB) : (hiA >= loB);
    const float c2  = ab ? (sb ? loA : hiB) : (sb ? hiA : loB);
    const int   c2i = ab ? (sb ? loAi : hiBi) : (sb ? hiAi : loBi);

    insert3_fast(c1, c1i, v0, i0, v1, i1, v2, i2);
    insert3_fast(c2, c2i, v0, i0, v1, i1, v2, i2);
  }

  // ---- wave-level tree merge (64 lanes) ----
#pragma unroll
  for (int off = 32; off > 0; off >>= 1) {
    float ov0 = __shfl_down(v0, off);
    int   oi0 = __shfl_down(i0, off);
    float ov1 = __shfl_down(v1, off);
    int   oi1 = __shfl_down(i1, off);
    float ov2 = __shfl_down(v2, off);
    int   oi2 = __shfl_down(i2, off);
    if (lane + off < 64) {
      insert3_full(ov0, oi0, v0, i0, v1, i1, v2, i2);
      insert3_full(ov1, oi1, v0, i0, v1, i1, v2, i2);
      insert3_full(ov2, oi2, v0, i0, v1, i1, v2, i2);
    }
  }

  if (lane == 0) {
    rv[wave * 3 + 0] = v0; ri[wave * 3 + 0] = i0;
    rv[wave * 3 + 1] = v1; ri[wave * 3 + 1] = i1;
    rv[wave * 3 + 2] = v2; ri[wave * 3 + 2] = i2;
  }
  __syncthreads();

  if (t == 0) {
#pragma unroll
    for (int w = 1; w < NW; ++w) {
      insert3_full(rv[w * 3 + 0], ri[w * 3 + 0], v0, i0, v1, i1, v2, i2);
      insert3_full(rv[w * 3 + 1], ri[w * 3 + 1], v0, i0, v1, i1, v2, i2);
      insert3_full(rv[w * 3 + 2], ri[w * 3 + 2], v0, i0, v1, i1, v2, i2);
    }

    float* __restrict__ nb = out;                      // neighbor_score
    float* __restrict__ ts = out + (size_t)rows * 3;   // topk_scores
    float* __restrict__ ti = out + (size_t)rows * 6;   // topk_index (as float)

    const int top = i0;
#pragma unroll
    for (int k = 0; k < 3; ++k) {
      int idx = top - 1 + k;
      idx = idx < 0 ? 0 : (idx > PW - 1 ? PW - 1 : idx);
      nb[row * 3 + k] = sx[idx];                       // row is in LDS
    }
    ts[row * 3 + 0] = v0;
    ts[row * 3 + 1] = v1;
    ts[row * 3 + 2] = v2;
    ti[row * 3 + 0] = (float)(i0 - PNLAG);
    ti[row * 3 + 1] = (float)(i1 - PNLAG);
    ti[row * 3 + 2] = (float)(i2 - PNLAG);
  }
}

extern "C" void kernel_launch(void* const* d_in, const int* in_sizes, int n_in,
                              void* d_out, int out_size, void* d_ws, size_t ws_size,
                              hipStream_t stream) {
  const float* x = (const float*)d_in[0];
  float* out = (float*)d_out;
  const int rows = in_sizes[0] / PW;   // 4096
  detect_peaks_kernel<<<rows, BLOCK, 0, stream>>>(x, out, rows);
}